// Round 1
// 545.075 us; speedup vs baseline: 1.0177x; 1.0177x over previous
//
#include <hip/hip_runtime.h>
#include <stdint.h>

// TPTransMatrix: out = x (16384 x 4096) times block_diag(blocks[0..7]) where
// blocks[kb] is 512x512. Grouped bf16-MFMA GEMM: M=16384, K=512, N=512, x8 groups.
//
// R1 changes vs baseline (554 us, gemm dispatch ~250 us, FETCH 2.16x ideal):
//  - XCD-aware wg remap: the 4 nt-WGs sharing an A slice now land on the SAME
//    XCD (stride-8 physical pid), so A refetches hit that XCD's L2 instead of
//    going to L3/HBM 4x.
//  - Swapped-operand MFMA (bf first, af second) -> lane holds 4 consecutive n
//    -> epilogue is one aligned dwordx4 nontemporal store per fragment
//    (was 4 scattered dwords); nt stores keep `out` from thrashing L2/L3.

#define HID 4096
#define KD  512
#define NKB 8
#define BM  128
#define BN  128
#define BK  32
#define MTILES 128            // 16384 / BM
#define NWG   (MTILES * NKB * 4)
#define ASTRIDE 40            // A LDS row stride in uint16 (80 B: 64 used + 16 pad)

typedef __attribute__((ext_vector_type(4))) float    f32x4;
typedef __attribute__((ext_vector_type(8))) short    s16x8;
typedef __attribute__((ext_vector_type(4))) uint32_t u32x4;

// bf16 transposed copy of blocks: g_bt[kb][c][b] = bf16(blocks[kb][b][c]).
__device__ uint16_t g_bt[(size_t)NKB * KD * KD];

__device__ __forceinline__ void async_copy16(const void* g, void* l) {
  __builtin_amdgcn_global_load_lds((const __attribute__((address_space(1))) void*)g,
                                   (__attribute__((address_space(3))) void*)l,
                                   16, 0, 0);
}

// fp32 -> bf16 RNE
__device__ __forceinline__ uint16_t f2bf_rne(float f) {
  uint32_t u = __float_as_uint(f);
  u += 0x7fffu + ((u >> 16) & 1u);
  return (uint16_t)(u >> 16);
}

// ---------------- prep: transpose + convert blocks -> g_bt ----------------
__global__ void convert_blocks_k(const float* __restrict__ blocks) {
  __shared__ float tile[32][33];                 // +1 pad: conflict-free transpose
  const int kb = blockIdx.z;
  const int c0 = blockIdx.x * 32;
  const int b0 = blockIdx.y * 32;
  const int tx = threadIdx.x;                    // 0..31
  const int ty = threadIdx.y;                    // 0..7
  const float* src = blocks + ((size_t)kb * KD + b0) * KD + c0;
#pragma unroll
  for (int i = 0; i < 4; ++i) {
    const int r = ty + i * 8;
    tile[r][tx] = src[(size_t)r * KD + tx];      // coalesced in c
  }
  __syncthreads();
  uint16_t* dst = g_bt + ((size_t)kb * KD + c0) * KD + b0;
#pragma unroll
  for (int i = 0; i < 4; ++i) {
    const int r = ty + i * 8;
    dst[(size_t)r * KD + tx] = f2bf_rne(tile[tx][r]);   // coalesced in b
  }
}

// ---------------- main grouped GEMM ----------------
__global__ void grouped_gemm_k(const float* __restrict__ x, float* __restrict__ out) {
  __shared__ uint16_t lA[BM * ASTRIDE];   // bf16 A tile, padded rows (2-way-free frag reads)
  __shared__ uint16_t lB[BN * BK];        // bf16 Bt tile, xor-swizzled 16B slots

  const int tid = threadIdx.x;

  // XCD-aware remap. HW round-robins pid%8 across XCDs; give each XCD a
  // contiguous logical chunk so the 4 nt-sharers of an A slice (logical
  // 4-aligned consecutive) are co-resident on ONE XCD, stride-8 in pid.
  const int pid = blockIdx.x;
  const int wg  = (pid & 7) * (NWG / 8) + (pid >> 3);
  const int nt  =  wg       & 3;          // n-tile fastest: 4 WGs share A slice (same-XCD L2)
  const int kb  = (wg >> 2) & 7;
  const int mt  =  wg >> 5;

  const int wave = tid >> 6;
  const int lane = tid & 63;
  const int ln   = lane & 15;
  const int qd   = lane >> 4;
  const int wm   = (wave & 1) * 64;
  const int wn   = (wave >> 1) * 64;

  // ---- A staging: thread -> (row am, k-half ah), 16 consecutive floats (64 B) ----
  const int am = tid >> 1;
  const int ah = tid & 1;
  const float* aptr = x + (size_t)(mt * BM + am) * HID + kb * KD + ah * 16;
  uint16_t* awr = lA + am * ASTRIDE + ah * 16;   // two 16B slots at +0, +8 (uint16 units)

  // ---- B staging: slots p = tid, tid+256; swizzle lives on the global-address side ----
  const int bn0 = tid >> 2;
  const int bs0 = (tid & 3) ^ (bn0 & 3) ^ ((bn0 >> 2) & 3);
  const int p1  = tid + 256;
  const int bn1 = p1 >> 2;
  const int bs1 = (p1 & 3) ^ (bn1 & 3) ^ ((bn1 >> 2) & 3);
  const uint16_t* bsrc0 = g_bt + (size_t)(kb * KD + nt * BN + bn0) * KD + bs0 * 8;
  const uint16_t* bsrc1 = g_bt + (size_t)(kb * KD + nt * BN + bn1) * KD + bs1 * 8;
  uint16_t* bdst0 = lB + tid * 8;                // lane-contiguous: required by global_load_lds
  uint16_t* bdst1 = lB + p1 * 8;

  // ---- fragment read bases ----
  const int sw = (ln & 3) ^ ((ln >> 2) & 3);     // matches staging swizzle (n bits == ln bits)
  const uint16_t* ard = lA + (wm + ln) * ASTRIDE + qd * 8;
  const uint16_t* brd = lB + ((wn + ln) * 4 + (qd ^ sw)) * 8;

  f32x4 acc[4][4];
#pragma unroll
  for (int mi = 0; mi < 4; ++mi)
#pragma unroll
    for (int ni = 0; ni < 4; ++ni)
      acc[mi][ni] = (f32x4){0.f, 0.f, 0.f, 0.f};

  for (int kk = 0; kk < KD / BK; ++kk) {
    const int k0 = kk * BK;
    // issue A global loads before the barrier so they fly during the wait
    const f32x4 a0 = *(const f32x4*)(aptr + k0);
    const f32x4 a1 = *(const f32x4*)(aptr + k0 + 4);
    const f32x4 a2 = *(const f32x4*)(aptr + k0 + 8);
    const f32x4 a3 = *(const f32x4*)(aptr + k0 + 12);

    __syncthreads();   // previous iter's frag reads done before overwrite

    async_copy16(bsrc0 + k0, bdst0);
    async_copy16(bsrc1 + k0, bdst1);

    // fp32 -> bf16 truncate-pack: 1 v_perm_b32 per 2 elements
    u32x4 w0, w1;
    w0.x = __builtin_amdgcn_perm(__float_as_uint(a0.y), __float_as_uint(a0.x), 0x07060302u);
    w0.y = __builtin_amdgcn_perm(__float_as_uint(a0.w), __float_as_uint(a0.z), 0x07060302u);
    w0.z = __builtin_amdgcn_perm(__float_as_uint(a1.y), __float_as_uint(a1.x), 0x07060302u);
    w0.w = __builtin_amdgcn_perm(__float_as_uint(a1.w), __float_as_uint(a1.z), 0x07060302u);
    w1.x = __builtin_amdgcn_perm(__float_as_uint(a2.y), __float_as_uint(a2.x), 0x07060302u);
    w1.y = __builtin_amdgcn_perm(__float_as_uint(a2.w), __float_as_uint(a2.z), 0x07060302u);
    w1.z = __builtin_amdgcn_perm(__float_as_uint(a3.y), __float_as_uint(a3.x), 0x07060302u);
    w1.w = __builtin_amdgcn_perm(__float_as_uint(a3.w), __float_as_uint(a3.z), 0x07060302u);
    *(u32x4*)(awr)     = w0;
    *(u32x4*)(awr + 8) = w1;

    __syncthreads();   // drains vmcnt (global_load_lds) + lgkm (ds_write)

    s16x8 af[4], bf[4];
#pragma unroll
    for (int mi = 0; mi < 4; ++mi) af[mi] = *(const s16x8*)(ard + mi * (16 * ASTRIDE));
#pragma unroll
    for (int ni = 0; ni < 4; ++ni) bf[ni] = *(const s16x8*)(brd + ni * (16 * 32));
    // Swapped operands: D = Bt x At  => lane(ln,qd) reg r holds
    // out[m = mbase+mi*16+ln][n = nbase+ni*16+qd*4+r]  -> dwordx4 stores.
#pragma unroll
    for (int mi = 0; mi < 4; ++mi)
#pragma unroll
      for (int ni = 0; ni < 4; ++ni)
        acc[mi][ni] = __builtin_amdgcn_mfma_f32_16x16x32_bf16(bf[ni], af[mi], acc[mi][ni], 0, 0, 0);
  }

  // epilogue: transposed C/D layout (operand swap): 4 consecutive n per reg.
  const int mbase = mt * BM + wm;
  const int nbase = kb * KD + nt * BN + wn + qd * 4;
#pragma unroll
  for (int mi = 0; mi < 4; ++mi) {
    float* orow = out + (size_t)(mbase + mi * 16 + ln) * HID + nbase;
#pragma unroll
    for (int ni = 0; ni < 4; ++ni)
      __builtin_nontemporal_store(acc[mi][ni], (f32x4*)(orow + ni * 16));
  }
}

extern "C" void kernel_launch(void* const* d_in, const int* in_sizes, int n_in,
                              void* d_out, int out_size, void* d_ws, size_t ws_size,
                              hipStream_t stream) {
  const float* x      = (const float*)d_in[0];   // [4,4096,4096] fp32 = 16384 x 4096
  const float* blocks = (const float*)d_in[1];   // [8,512,512] fp32
  float* out = (float*)d_out;
  (void)d_ws; (void)ws_size; (void)in_sizes; (void)n_in; (void)out_size;

  convert_blocks_k<<<dim3(16, 16, 8), dim3(32, 8, 1), 0, stream>>>(blocks);
  grouped_gemm_k<<<dim3(NWG, 1, 1), dim3(256, 1, 1), 0, stream>>>(x, out);
}

// Round 2
// 543.785 us; speedup vs baseline: 1.0201x; 1.0024x over previous
//
#include <hip/hip_runtime.h>
#include <stdint.h>

// TPTransMatrix: out = x (16384 x 4096) times block_diag(blocks[0..7]) where
// blocks[kb] is 512x512. Grouped bf16-MFMA GEMM: M=16384, K=512, N=512, x8 groups.
//
// R2: single-barrier pipelined K-loop. R1 showed traffic -27% with zero time
// delta -> latency-bound, not BW-bound. Old structure exposed ~2 full memory
// latencies per K-step (load->barrier->use, copy->barrier-drain). Now both LDS
// tiles are double-buffered; step kk issues ALL of step kk+1's memory (B
// global_load_lds into buffer q, A global->regs) at the top, computes kk's
// MFMAs, packs A(kk+1) into LDS q, then ONE __syncthreads. Load-to-use
// distance ~= one full iteration of work instead of ~0.

#define HID 4096
#define KD  512
#define NKB 8
#define BM  128
#define BN  128
#define BK  32
#define NKK (KD / BK)         // 16 K-steps
#define MTILES 128            // 16384 / BM
#define NWG   (MTILES * NKB * 4)
#define ASTRIDE 40            // A LDS row stride in uint16 (80 B: 64 used + 16 pad)

typedef __attribute__((ext_vector_type(4))) float    f32x4;
typedef __attribute__((ext_vector_type(8))) short    s16x8;
typedef __attribute__((ext_vector_type(4))) uint32_t u32x4;

// bf16 transposed copy of blocks: g_bt[kb][c][b] = bf16(blocks[kb][b][c]).
__device__ uint16_t g_bt[(size_t)NKB * KD * KD];

__device__ __forceinline__ void async_copy16(const void* g, void* l) {
  __builtin_amdgcn_global_load_lds((const __attribute__((address_space(1))) void*)g,
                                   (__attribute__((address_space(3))) void*)l,
                                   16, 0, 0);
}

// fp32 -> bf16 RNE
__device__ __forceinline__ uint16_t f2bf_rne(float f) {
  uint32_t u = __float_as_uint(f);
  u += 0x7fffu + ((u >> 16) & 1u);
  return (uint16_t)(u >> 16);
}

// ---------------- prep: transpose + convert blocks -> g_bt ----------------
__global__ void convert_blocks_k(const float* __restrict__ blocks) {
  __shared__ float tile[32][33];                 // +1 pad: conflict-free transpose
  const int kb = blockIdx.z;
  const int c0 = blockIdx.x * 32;
  const int b0 = blockIdx.y * 32;
  const int tx = threadIdx.x;                    // 0..31
  const int ty = threadIdx.y;                    // 0..7
  const float* src = blocks + ((size_t)kb * KD + b0) * KD + c0;
#pragma unroll
  for (int i = 0; i < 4; ++i) {
    const int r = ty + i * 8;
    tile[r][tx] = src[(size_t)r * KD + tx];      // coalesced in c
  }
  __syncthreads();
  uint16_t* dst = g_bt + ((size_t)kb * KD + c0) * KD + b0;
#pragma unroll
  for (int i = 0; i < 4; ++i) {
    const int r = ty + i * 8;
    dst[(size_t)r * KD + tx] = f2bf_rne(tile[tx][r]);   // coalesced in b
  }
}

// ---------------- main grouped GEMM ----------------
__global__ void grouped_gemm_k(const float* __restrict__ x, float* __restrict__ out) {
  __shared__ uint16_t lA[2][BM * ASTRIDE];   // double-buffered bf16 A tile
  __shared__ uint16_t lB[2][BN * BK];        // double-buffered bf16 Bt tile (swizzled slots)

  const int tid = threadIdx.x;

  // XCD-aware remap: 4 nt-sharers of an A slice land on one XCD (stride-8 pid).
  const int pid = blockIdx.x;
  const int wg  = (pid & 7) * (NWG / 8) + (pid >> 3);
  const int nt  =  wg       & 3;
  const int kb  = (wg >> 2) & 7;
  const int mt  =  wg >> 5;

  const int wave = tid >> 6;
  const int lane = tid & 63;
  const int ln   = lane & 15;
  const int qd   = lane >> 4;
  const int wm   = (wave & 1) * 64;
  const int wn   = (wave >> 1) * 64;

  // ---- A staging: thread -> (row am, k-half ah), 16 consecutive floats (64 B) ----
  const int am = tid >> 1;
  const int ah = tid & 1;
  const float* aptr = x + (size_t)(mt * BM + am) * HID + kb * KD + ah * 16;
  const int awo = am * ASTRIDE + ah * 16;        // uint16 offset within a buffer

  // ---- B staging: slots p = tid, tid+256; swizzle lives on the global-address side ----
  const int bn0 = tid >> 2;
  const int bs0 = (tid & 3) ^ (bn0 & 3) ^ ((bn0 >> 2) & 3);
  const int p1  = tid + 256;
  const int bn1 = p1 >> 2;
  const int bs1 = (p1 & 3) ^ (bn1 & 3) ^ ((bn1 >> 2) & 3);
  const uint16_t* bsrc0 = g_bt + (size_t)(kb * KD + nt * BN + bn0) * KD + bs0 * 8;
  const uint16_t* bsrc1 = g_bt + (size_t)(kb * KD + nt * BN + bn1) * KD + bs1 * 8;
  const int bdo0 = tid * 8;                      // lane-contiguous dst offsets
  const int bdo1 = p1 * 8;

  // ---- fragment read bases (offsets within a buffer) ----
  const int sw   = (ln & 3) ^ ((ln >> 2) & 3);
  const int ardo = (wm + ln) * ASTRIDE + qd * 8;
  const int brdo = ((wn + ln) * 4 + (qd ^ sw)) * 8;

  f32x4 acc[4][4];
#pragma unroll
  for (int mi = 0; mi < 4; ++mi)
#pragma unroll
    for (int ni = 0; ni < 4; ++ni)
      acc[mi][ni] = (f32x4){0.f, 0.f, 0.f, 0.f};

  // ---------------- prologue: stage K-step 0 into buffer 0 ----------------
  {
    const f32x4 a0 = *(const f32x4*)(aptr);
    const f32x4 a1 = *(const f32x4*)(aptr + 4);
    const f32x4 a2 = *(const f32x4*)(aptr + 8);
    const f32x4 a3 = *(const f32x4*)(aptr + 12);
    async_copy16(bsrc0, &lB[0][bdo0]);
    async_copy16(bsrc1, &lB[0][bdo1]);
    u32x4 w0, w1;
    w0.x = __builtin_amdgcn_perm(__float_as_uint(a0.y), __float_as_uint(a0.x), 0x07060302u);
    w0.y = __builtin_amdgcn_perm(__float_as_uint(a0.w), __float_as_uint(a0.z), 0x07060302u);
    w0.z = __builtin_amdgcn_perm(__float_as_uint(a1.y), __float_as_uint(a1.x), 0x07060302u);
    w0.w = __builtin_amdgcn_perm(__float_as_uint(a1.w), __float_as_uint(a1.z), 0x07060302u);
    w1.x = __builtin_amdgcn_perm(__float_as_uint(a2.y), __float_as_uint(a2.x), 0x07060302u);
    w1.y = __builtin_amdgcn_perm(__float_as_uint(a2.w), __float_as_uint(a2.z), 0x07060302u);
    w1.z = __builtin_amdgcn_perm(__float_as_uint(a3.y), __float_as_uint(a3.x), 0x07060302u);
    w1.w = __builtin_amdgcn_perm(__float_as_uint(a3.w), __float_as_uint(a3.z), 0x07060302u);
    *(u32x4*)(&lA[0][awo])     = w0;
    *(u32x4*)(&lA[0][awo + 8]) = w1;
  }
  __syncthreads();

  // ---------------- pipelined K-loop: one barrier per step ----------------
#pragma unroll
  for (int kk = 0; kk < NKK; ++kk) {
    const int p = kk & 1;
    const int q = p ^ 1;

    f32x4 a0, a1, a2, a3;
    if (kk + 1 < NKK) {
      const int k1 = (kk + 1) * BK;
      // issue next step's memory FIRST: it flies under this step's compute
      async_copy16(bsrc0 + k1, &lB[q][bdo0]);
      async_copy16(bsrc1 + k1, &lB[q][bdo1]);
      a0 = *(const f32x4*)(aptr + k1);
      a1 = *(const f32x4*)(aptr + k1 + 4);
      a2 = *(const f32x4*)(aptr + k1 + 8);
      a3 = *(const f32x4*)(aptr + k1 + 12);
    }

    // current step's fragments + MFMA (data guaranteed by previous barrier)
    s16x8 af[4], bf[4];
#pragma unroll
    for (int mi = 0; mi < 4; ++mi) af[mi] = *(const s16x8*)(&lA[p][ardo + mi * (16 * ASTRIDE)]);
#pragma unroll
    for (int ni = 0; ni < 4; ++ni) bf[ni] = *(const s16x8*)(&lB[p][brdo + ni * (16 * 32)]);
    // Swapped operands: D = Bt x At  => lane(ln,qd) reg r holds
    // out[m = mbase+mi*16+ln][n = nbase+ni*16+qd*4+r]  -> dwordx4 stores.
#pragma unroll
    for (int mi = 0; mi < 4; ++mi)
#pragma unroll
      for (int ni = 0; ni < 4; ++ni)
        acc[mi][ni] = __builtin_amdgcn_mfma_f32_16x16x32_bf16(bf[ni], af[mi], acc[mi][ni], 0, 0, 0);

    if (kk + 1 < NKK) {
      // pack A(kk+1): its loads have had frag-reads + 16 MFMAs to land
      u32x4 w0, w1;
      w0.x = __builtin_amdgcn_perm(__float_as_uint(a0.y), __float_as_uint(a0.x), 0x07060302u);
      w0.y = __builtin_amdgcn_perm(__float_as_uint(a0.w), __float_as_uint(a0.z), 0x07060302u);
      w0.z = __builtin_amdgcn_perm(__float_as_uint(a1.y), __float_as_uint(a1.x), 0x07060302u);
      w0.w = __builtin_amdgcn_perm(__float_as_uint(a1.w), __float_as_uint(a1.z), 0x07060302u);
      w1.x = __builtin_amdgcn_perm(__float_as_uint(a2.y), __float_as_uint(a2.x), 0x07060302u);
      w1.y = __builtin_amdgcn_perm(__float_as_uint(a2.w), __float_as_uint(a2.z), 0x07060302u);
      w1.z = __builtin_amdgcn_perm(__float_as_uint(a3.y), __float_as_uint(a3.x), 0x07060302u);
      w1.w = __builtin_amdgcn_perm(__float_as_uint(a3.w), __float_as_uint(a3.z), 0x07060302u);
      *(u32x4*)(&lA[q][awo])     = w0;
      *(u32x4*)(&lA[q][awo + 8]) = w1;
      __syncthreads();   // drains this step's vmem (already landed) + ds_writes
    }
  }

  // epilogue: transposed C/D layout (operand swap): 4 consecutive n per reg.
  const int mbase = mt * BM + wm;
  const int nbase = kb * KD + nt * BN + wn + qd * 4;
#pragma unroll
  for (int mi = 0; mi < 4; ++mi) {
    float* orow = out + (size_t)(mbase + mi * 16 + ln) * HID + nbase;
#pragma unroll
    for (int ni = 0; ni < 4; ++ni)
      __builtin_nontemporal_store(acc[mi][ni], (f32x4*)(orow + ni * 16));
  }
}

extern "C" void kernel_launch(void* const* d_in, const int* in_sizes, int n_in,
                              void* d_out, int out_size, void* d_ws, size_t ws_size,
                              hipStream_t stream) {
  const float* x      = (const float*)d_in[0];   // [4,4096,4096] fp32 = 16384 x 4096
  const float* blocks = (const float*)d_in[1];   // [8,512,512] fp32
  float* out = (float*)d_out;
  (void)d_ws; (void)ws_size; (void)in_sizes; (void)n_in; (void)out_size;

  convert_blocks_k<<<dim3(16, 16, 8), dim3(32, 8, 1), 0, stream>>>(blocks);
  grouped_gemm_k<<<dim3(NWG, 1, 1), dim3(256, 1, 1), 0, stream>>>(x, out);
}